// Round 14
// baseline (213.943 us; speedup 1.0000x reference)
//
#include <hip/hip_runtime.h>
#include <hip/hip_bf16.h>

#define N_NODES 100000
#define N_EDGES 1000000
#define SCAN_B 256
#define N_BLOCKS_SCAN ((N_NODES + SCAN_B - 1) / SCAN_B)   // 391
#define H_BLOCKS 1024

// superrange partitioning (hist/coff granularity)
#define RANGES 4
#define RSIZE  25000
#define RWORDS 12500          // u32 words (2 x u16 per word)
#define CHUNKS 32
#define CHUNK_EDGES (N_EDGES / CHUNKS)   // 31250

// ---------------- workspace layout (bytes) ---------------- (~46 MB)
// ghist_s   [0         .. 6,400,000)   u32[128*12500]
// ghist_r   [6,400,000 ..12,800,000)   u32[128*12500]
// coff      [12,800,000..25,600,000)   int[128*25000]
// cnt_r     [25,600,000..26,000,000)   int[N]
// row_start [26,000,000..26,400,016)   int[N+1]
// blockSums [26,400,016..26,401,580)   int[391]
// rs        [26,403,200..26,803,200)   float[N]
// col       [26,803,200..30,803,200)   int[E]
// h16       [30,803,200..43,603,200)   ushort[N*64] bf16
// z         [43,603,200..44,003,200)   float[N]
// rank16    [44,003,200..46,003,200)   ushort[E]  in-(range,chunk) rank
// NO memset: every buffer densely overwritten before first read.

__device__ __forceinline__ unsigned f32_to_bf16(float v) {
    unsigned u = __float_as_uint(v);
    return (u + 0x7fffu + ((u >> 16) & 1u)) >> 16;     // RNE
}

// Histogram both index arrays into per-(arr,superrange,chunk) private copies.
// Receiver blocks additionally record each edge's in-(range,chunk) rank
// (the LDS atomicAdd's old value) -- consumed by the atomic-free k_fill2.
__global__ void k_hist(const int* __restrict__ senders,
                       const int* __restrict__ receivers,
                       unsigned* __restrict__ ghist_s,
                       unsigned* __restrict__ ghist_r,
                       unsigned short* __restrict__ rank16) {
    __shared__ unsigned lds[RWORDS];   // 50 KB
    int blk = blockIdx.x;              // [0, 256)
    int arr = blk >> 7;
    int rem = blk & 127;
    int r   = rem >> 5;
    int c   = rem & 31;
    const int* __restrict__ src = arr ? receivers : senders;
    unsigned* __restrict__ gh   = arr ? ghist_r : ghist_s;
    int t = threadIdx.x;

    for (int w = t; w < RWORDS; w += 1024) lds[w] = 0u;
    __syncthreads();

    int base = r * RSIZE;
    int beg  = c * CHUNK_EDGES;
    int end  = beg + CHUNK_EDGES;
    for (int i = beg + t; i < end; i += 1024) {
        unsigned idx = (unsigned)(src[i] - base);
        if (idx < (unsigned)RSIZE) {
            int sh = (idx & 1) * 16;
            unsigned old = atomicAdd(&lds[idx >> 1], 1u << sh);
            if (arr) rank16[i] = (unsigned short)((old >> sh) & 0xffffu);
        }
    }
    __syncthreads();

    unsigned* __restrict__ dst = gh + (size_t)rem * RWORDS;
    for (int w = t; w < RWORDS; w += 1024) dst[w] = lds[w];
}

// Merged reduce + scanA: per node, sum chunk copies -> cnt_r (recv) and
// rs (send); block-level inclusive scan of cnt -> blockSums.
__global__ void k_scanA2(const unsigned* __restrict__ ghist_s,
                         const unsigned* __restrict__ ghist_r,
                         int* __restrict__ cnt_r, float* __restrict__ rs,
                         int* __restrict__ blockSums) {
    __shared__ int s[SCAN_B];
    int t = threadIdx.x;
    int idx = blockIdx.x * SCAN_B + t;
    int v = 0;
    if (idx < N_NODES) {
        int r = idx / RSIZE;
        int bin = idx - r * RSIZE;
        int w = bin >> 1, sh = (bin & 1) * 16;
        const unsigned* __restrict__ gr = ghist_r + (size_t)(r * CHUNKS) * RWORDS + w;
        const unsigned* __restrict__ gs = ghist_s + (size_t)(r * CHUNKS) * RWORDS + w;
        unsigned sr_ = 0, ss_ = 0;
#pragma unroll
        for (int c = 0; c < CHUNKS; ++c) {
            sr_ += (gr[(size_t)c * RWORDS] >> sh) & 0xffffu;
            ss_ += (gs[(size_t)c * RWORDS] >> sh) & 0xffffu;
        }
        v = (int)sr_;
        cnt_r[idx] = v;
        rs[idx] = rsqrtf(fmaxf((float)ss_, 1.0f));
    }
    s[t] = v;
    __syncthreads();
    for (int off = 1; off < SCAN_B; off <<= 1) {
        int x = (t >= off) ? s[t - off] : 0;
        __syncthreads();
        s[t] += x;
        __syncthreads();
    }
    if (t == SCAN_B - 1) blockSums[blockIdx.x] = s[t];
}

// Merged kernel: blocks [0, 391) = scanCD (row_start + coff, with inline
// global offset); blocks [391, 391+H_BLOCKS) = k_h (dense MLP layer 1).
__global__ void k_scanCD_h(const int* __restrict__ cnt_r,
                           const int* __restrict__ blockSums,
                           const unsigned* __restrict__ ghist_r,
                           int* __restrict__ row_start,
                           int* __restrict__ coff,
                           const float* __restrict__ emb,
                           const float* __restrict__ rs,
                           const float* __restrict__ W1,
                           unsigned short* __restrict__ h16) {
    __shared__ int s[SCAN_B];
    int t = threadIdx.x;
    int b = blockIdx.x;

    if (b < N_BLOCKS_SCAN) {
        // ---- block offset = sum of blockSums[0..b) ----
        int acc = 0;
        for (int j = t; j < b; j += SCAN_B) acc += blockSums[j];
        s[t] = acc;
        __syncthreads();
        for (int off = SCAN_B / 2; off > 0; off >>= 1) {
            if (t < off) s[t] += s[t + off];
            __syncthreads();
        }
        int blockOff = s[0];
        __syncthreads();

        // ---- inclusive scan of this block's counts ----
        int idx = b * SCAN_B + t;
        int v = (idx < N_NODES) ? cnt_r[idx] : 0;
        s[t] = v;
        __syncthreads();
        for (int off = 1; off < SCAN_B; off <<= 1) {
            int x = (t >= off) ? s[t - off] : 0;
            __syncthreads();
            s[t] += x;
            __syncthreads();
        }
        if (idx < N_NODES) {
            int run = blockOff + s[t] - v;   // exclusive prefix
            row_start[idx] = run;
            int r = idx / RSIZE;
            int bin = idx - r * RSIZE;
            int w = bin >> 1, sh = (bin & 1) * 16;
            const unsigned* __restrict__ gr = ghist_r + (size_t)(r * CHUNKS) * RWORDS + w;
            int* __restrict__ co = coff + (size_t)(r * CHUNKS) * RSIZE + bin;
#pragma unroll
            for (int c = 0; c < CHUNKS; ++c) {
                co[(size_t)c * RSIZE] = run;
                run += (int)((gr[(size_t)c * RWORDS] >> sh) & 0xffffu);
            }
        }
        if (b == 0 && t == 0) row_start[N_NODES] = N_EDGES;
    } else {
        // ---- h16[n][lane] = bf16( ((emb[n]*rs[n]) @ W1)[lane] ) ----
        int lane = t & 63;
        int wib  = t >> 6;                          // 0..3
        int gw   = (b - N_BLOCKS_SCAN) * 4 + wib;   // 4096 waves
        const int nw = H_BLOCKS * 4;

        float w1c[64];
#pragma unroll
        for (int k = 0; k < 64; ++k) w1c[k] = W1[k * 64 + lane];

        for (int n = gw; n < N_NODES; n += nw) {
            float e = emb[(size_t)n * 64 + lane] * rs[n];
            float a = 0.f;
            int ei = __float_as_int(e);
#pragma unroll
            for (int k = 0; k < 64; ++k)
                a += __int_as_float(__builtin_amdgcn_readlane(ei, k)) * w1c[k];
            h16[(size_t)n * 64 + lane] = (unsigned short)f32_to_bf16(a);
        }
    }
}

// Atomic-free, LDS-free CSR fill: thread per edge, one pass.
// col[ coff[range][chunk][bin] + rank16[i] ] = senders[i]
__global__ void k_fill2(const int* __restrict__ senders,
                        const int* __restrict__ receivers,
                        const int* __restrict__ coff,
                        const unsigned short* __restrict__ rank16,
                        int* __restrict__ col) {
    int i = blockIdx.x * blockDim.x + threadIdx.x;
    if (i >= N_EDGES) return;
    int rv = receivers[i];
    int r  = rv / RSIZE;
    int bin = rv - r * RSIZE;
    int c  = i / CHUNK_EDGES;
    int co = coff[(size_t)(r * CHUNKS + c) * RSIZE + bin];
    col[co + (int)rank16[i]] = senders[i];
}

// Half-wave node mapping: lanes 0-31 -> node 2w, lanes 32-63 -> node 2w+1.
// Each lane loads ushort2 (2 bf16 features); 4-deep unroll -> 8 outstanding
// gathers per wave.
__global__ void k_agg_post(const int* __restrict__ row_start,
                           const int* __restrict__ col,
                           const unsigned* __restrict__ h32,   // h16 as u32 pairs
                           const float* __restrict__ W2,
                           const float* __restrict__ b2,
                           float* __restrict__ z) {
    int gtid = blockIdx.x * blockDim.x + threadIdx.x;
    int wid  = gtid >> 6;
    int lane = threadIdx.x & 63;
    int half = lane >> 5;              // which node of the pair
    int hl   = lane & 31;              // lane within half-wave
    int n = wid * 2 + half;
    if (n >= N_NODES) return;

    int start = row_start[n];
    int end   = row_start[n + 1];
    float a0 = 0.f, a1 = 0.f;          // features 2*hl, 2*hl+1
    int i = start;
    for (; i + 3 < end; i += 4) {
        int s0 = col[i], s1 = col[i + 1], s2 = col[i + 2], s3 = col[i + 3];
        unsigned u0 = h32[(size_t)s0 * 32 + hl];
        unsigned u1 = h32[(size_t)s1 * 32 + hl];
        unsigned u2 = h32[(size_t)s2 * 32 + hl];
        unsigned u3 = h32[(size_t)s3 * 32 + hl];
        a0 += (__uint_as_float(u0 << 16) + __uint_as_float(u1 << 16)) +
              (__uint_as_float(u2 << 16) + __uint_as_float(u3 << 16));
        a1 += (__uint_as_float(u0 & 0xffff0000u) + __uint_as_float(u1 & 0xffff0000u)) +
              (__uint_as_float(u2 & 0xffff0000u) + __uint_as_float(u3 & 0xffff0000u));
    }
    for (; i < end; ++i) {
        unsigned u = h32[(size_t)col[i] * 32 + hl];
        a0 += __uint_as_float(u << 16);
        a1 += __uint_as_float(u & 0xffff0000u);
    }

    float rsq = rsqrtf(fmaxf((float)(end - start), 1.0f));
    float x0 = a0 * rsq, x1 = a1 * rsq;
    x0 = (x0 > 0.f) ? x0 : 0.01f * x0;
    x1 = (x1 > 0.f) ? x1 : 0.01f * x1;
    float2 w2 = ((const float2*)W2)[hl];
    float p = x0 * w2.x + x1 * w2.y;
#pragma unroll
    for (int off = 16; off > 0; off >>= 1) p += __shfl_xor(p, off, 64);
    if (hl == 0) z[n] = p + b2[0];
}

// thread per node: out[n] = sigmoid( sum over in-edges z[s] )  (z L2-resident)
__global__ void k_agg2_sigmoid(const int* __restrict__ row_start,
                               const int* __restrict__ col,
                               const float* __restrict__ z,
                               float* __restrict__ out) {
    int n = blockIdx.x * blockDim.x + threadIdx.x;
    if (n >= N_NODES) return;
    int start = row_start[n];
    int end   = row_start[n + 1];
    float acc = 0.f;
    int i = start;
    for (; i + 3 < end; i += 4) {
        float a = z[col[i]],     b = z[col[i + 1]];
        float c = z[col[i + 2]], d = z[col[i + 3]];
        acc += (a + b) + (c + d);
    }
    for (; i < end; ++i) acc += z[col[i]];
    out[n] = 1.0f / (1.0f + expf(-acc));
}

extern "C" void kernel_launch(void* const* d_in, const int* in_sizes, int n_in,
                              void* d_out, int out_size, void* d_ws, size_t ws_size,
                              hipStream_t stream) {
    const int* senders    = (const int*)d_in[1];
    const int* receivers  = (const int*)d_in[2];
    const float* emb      = (const float*)d_in[3];
    const float* W1       = (const float*)d_in[4];
    const float* W2       = (const float*)d_in[5];
    const float* b2       = (const float*)d_in[6];
    float* out            = (float*)d_out;

    char* ws = (char*)d_ws;
    unsigned*       ghist_s   = (unsigned*)(ws);
    unsigned*       ghist_r   = (unsigned*)(ws + 6400000);
    int*            coff      = (int*)(ws + 12800000);
    int*            cnt_r     = (int*)(ws + 25600000);
    int*            row_start = (int*)(ws + 26000000);
    int*            blockSums = (int*)(ws + 26400016);
    float*          rs        = (float*)(ws + 26403200);
    int*            col       = (int*)(ws + 26803200);
    unsigned short* h16       = (unsigned short*)(ws + 30803200);
    float*          z         = (float*)(ws + 43603200);
    unsigned short* rank16    = (unsigned short*)(ws + 44003200);

    const int B = 256;
    k_hist<<<2 * RANGES * CHUNKS, 1024, 0, stream>>>(senders, receivers, ghist_s, ghist_r, rank16);
    k_scanA2<<<N_BLOCKS_SCAN, SCAN_B, 0, stream>>>(ghist_s, ghist_r, cnt_r, rs, blockSums);
    k_scanCD_h<<<N_BLOCKS_SCAN + H_BLOCKS, B, 0, stream>>>(
        cnt_r, blockSums, ghist_r, row_start, coff, emb, rs, W1, h16);
    k_fill2<<<(N_EDGES + B - 1) / B, B, 0, stream>>>(senders, receivers, coff, rank16, col);
    // 2 nodes per wave -> 50000 waves -> 12500 blocks of 256
    k_agg_post<<<12500, B, 0, stream>>>(row_start, col, (const unsigned*)h16, W2, b2, z);
    k_agg2_sigmoid<<<(N_NODES + B - 1) / B, B, 0, stream>>>(row_start, col, z, out);
}